// Round 1
// 617.459 us; speedup vs baseline: 1.0384x; 1.0384x over previous
//
#include <hip/hip_runtime.h>

using short8  = __attribute__((ext_vector_type(8))) short;
using short4v = __attribute__((ext_vector_type(4))) short;
using float4v = __attribute__((ext_vector_type(4))) float;
using bf16x2  = __attribute__((ext_vector_type(2))) __bf16;

#define IMG  224
#define CDIM 96
#define NTOK 49
#define STQ  104   // q_s/k_s row stride (shorts): 208B = 13*16 -> aligned, 2-way-free b128 reads
#define STV  72    // v_sT row stride (shorts): 144B = 9*16 -> aligned b128/b64

// Native f32->bf16 (RNE) — compiler emits v_cvt_pk_bf16_f32 for pairs (learn_hip m240).
__device__ __forceinline__ unsigned short f2bf(float f) {
  union { __bf16 h; unsigned short u; } cv;
  cv.h = (__bf16)f;
  return cv.u;
}

__device__ __forceinline__ unsigned pk2(float lo, float hi) {
  union { bf16x2 v; unsigned u; } cv;
  cv.v = bf16x2{(__bf16)lo, (__bf16)hi};
  return cv.u;
}

// Pre-pass: w_qkv [96x288], w_proj [96x96] -> bf16 B-fragment blobs.
// Slot layout: blob[(ks*NT + nt)*64 + lane][j] = W[32*ks + (lane>>4)*8 + j][16*nt + (lane&15)]
__global__ void prep_weights(const float* __restrict__ wqkv,
                             const float* __restrict__ wproj,
                             unsigned short* __restrict__ blob) {
  int tid = blockIdx.x * 256 + threadIdx.x;
  if (tid < 3456) {                       // 3 ks * 18 nt * 64 lanes
    int ks = tid / (18 * 64);
    int rem = tid % (18 * 64);
    int nt = rem / 64;
    int lane = rem % 64;
    int k0 = 32 * ks + (lane >> 4) * 8;
    int n  = 16 * nt + (lane & 15);
    unsigned short* dst = blob + tid * 8;
#pragma unroll
    for (int j = 0; j < 8; ++j) dst[j] = f2bf(wqkv[(k0 + j) * 288 + n]);
  } else if (tid < 4608) {                // 3 ks * 6 nt * 64 lanes
    int t = tid - 3456;
    int ks = t / (6 * 64);
    int rem = t % (6 * 64);
    int nt = rem / 64;
    int lane = rem % 64;
    int k0 = 32 * ks + (lane >> 4) * 8;
    int n  = 16 * nt + (lane & 15);
    unsigned short* dst = blob + 3456 * 8 + t * 8;
#pragma unroll
    for (int j = 0; j < 8; ++j) dst[j] = f2bf(wproj[(k0 + j) * 96 + n]);
  }
}

// One block (4 waves) per 7x7 window. Wave w owns token M-tile w (tokens 16w..16w+15, padded to 64).
// LDS: q_s (q scaled by cexp, later att), k_s (k, later P scratch), v_sT (v transposed).
// 40592 B -> 4 blocks/CU.
__global__ __launch_bounds__(256, 4)
void swin_kernel(const float* __restrict__ x,
                 const float* __restrict__ bqkv,
                 const float* __restrict__ bproj,
                 const unsigned short* __restrict__ blob,
                 float* __restrict__ out) {
  __shared__ __align__(16) unsigned short q_s[64 * STQ];   // q [token][d]*cexp; later att
  __shared__ __align__(16) unsigned short k_s[64 * STQ];   // k [token][d]; later P [q][key]
  __shared__ __align__(16) unsigned short v_sT[96 * STV];  // v [d][token]

  const int tid  = threadIdx.x;
  const int lane = tid & 63;
  const int wv   = tid >> 6;      // wave id == M-tile
  const int l15  = lane & 15;
  const int quad = lane >> 4;

  const int wid = blockIdx.x;
  const int b   = wid >> 10;      // / (32*32)
  const int rem = wid & 1023;
  const int wr  = rem >> 5;
  const int wc  = rem & 31;

  const float4v ZERO4 = {0.f, 0.f, 0.f, 0.f};
  const int trow = 16 * wv + quad * 4;   // C-layout row base (token) for this lane
  const float CEXP = 0.25500526034059f;  // (1/sqrt(32)) * log2(e), folded into q

  // ---------------- Phase 1: QKV = x_win @ w_qkv + b ----------------
  // A-frag: lane holds x[token = 16*wv + l15][ch = 32*ks + quad*8 + j]
  short8 afr[3];
  {
    int ta = 16 * wv + l15;
    if (ta < NTOK) {
      int r = ta / 7, c = ta - 7 * r;
      int gh = wr * 7 + r + 3; if (gh >= IMG) gh -= IMG;
      int gw = wc * 7 + c + 3; if (gw >= IMG) gw -= IMG;
      const float* xp = x + ((b * IMG + gh) * IMG + gw) * CDIM + quad * 8;
#pragma unroll
      for (int ks = 0; ks < 3; ++ks) {
        float4v v0 = *(const float4v*)(xp + 32 * ks);
        float4v v1 = *(const float4v*)(xp + 32 * ks + 4);
        union { unsigned u[4]; short8 v; } cv;
        cv.u[0] = pk2(v0[0], v0[1]);
        cv.u[1] = pk2(v0[2], v0[3]);
        cv.u[2] = pk2(v1[0], v1[1]);
        cv.u[3] = pk2(v1[2], v1[3]);
        afr[ks] = cv.v;
      }
    } else {
      short8 z = {0, 0, 0, 0, 0, 0, 0, 0};
      afr[0] = z; afr[1] = z; afr[2] = z;
    }
  }

  const short8* bq = (const short8*)blob;
#pragma unroll
  for (int nt = 0; nt < 18; ++nt) {
    float4v acc = ZERO4;
#pragma unroll
    for (int ks = 0; ks < 3; ++ks) {
      short8 bf = bq[(ks * 18 + nt) * 64 + lane];
      acc = __builtin_amdgcn_mfma_f32_16x16x32_bf16(afr[ks], bf, acc, 0, 0, 0);
    }
    int col = 16 * nt + l15;
    float bias = bqkv[col];
    if (nt < 6) {                        // q -> q_s[token][d], pre-scaled by cexp
      unsigned d01 = pk2((acc[0] + bias) * CEXP, (acc[1] + bias) * CEXP);
      unsigned d23 = pk2((acc[2] + bias) * CEXP, (acc[3] + bias) * CEXP);
      unsigned short* p = &q_s[trow * STQ + col];
      p[0]       = (unsigned short)d01;
      p[STQ]     = (unsigned short)(d01 >> 16);
      p[2 * STQ] = (unsigned short)d23;
      p[3 * STQ] = (unsigned short)(d23 >> 16);
    } else if (nt < 12) {                // k -> k_s[token][d]
      unsigned d01 = pk2(acc[0] + bias, acc[1] + bias);
      unsigned d23 = pk2(acc[2] + bias, acc[3] + bias);
      unsigned short* p = &k_s[trow * STQ + (col - 96)];
      p[0]       = (unsigned short)d01;
      p[STQ]     = (unsigned short)(d01 >> 16);
      p[2 * STQ] = (unsigned short)d23;
      p[3 * STQ] = (unsigned short)(d23 >> 16);
    } else {                             // v -> v_sT[d][token]; zero padded tokens (>=49)
      float f0 = (trow + 0 < NTOK) ? acc[0] + bias : 0.f;
      float f1 = (trow + 1 < NTOK) ? acc[1] + bias : 0.f;
      float f2 = (trow + 2 < NTOK) ? acc[2] + bias : 0.f;
      float f3 = (trow + 3 < NTOK) ? acc[3] + bias : 0.f;
      union { unsigned u[2]; short4v v; } cv;
      cv.u[0] = pk2(f0, f1);
      cv.u[1] = pk2(f2, f3);
      *(short4v*)&v_sT[(col - 192) * STV + trow] = cv.v;
    }
  }
  __syncthreads();

  // ---------------- Phase 2a: S = q k^T for ALL heads; P = exp2(S) packed in regs ----
  // No max-sub (softmax is shift-invariant; |S| is O(10), f32 exp2 cannot overflow).
  unsigned pp[3][4][2];   // [head][key-tile][row-pair], bf16x2 (rows 2m,2m+1)
#pragma unroll
  for (int h = 0; h < 3; ++h) {
    short8 qa = *(const short8*)&q_s[(16 * wv + l15) * STQ + 32 * h + quad * 8];
#pragma unroll
    for (int nt = 0; nt < 4; ++nt) {
      short8 kb = *(const short8*)&k_s[(16 * nt + l15) * STQ + 32 * h + quad * 8];
      float4v s = __builtin_amdgcn_mfma_f32_16x16x32_bf16(qa, kb, ZERO4, 0, 0, 0);
      pp[h][nt][0] = pk2(__builtin_amdgcn_exp2f(s[0]), __builtin_amdgcn_exp2f(s[1]));
      pp[h][nt][1] = pk2(__builtin_amdgcn_exp2f(s[2]), __builtin_amdgcn_exp2f(s[3]));
    }
  }
  __syncthreads();   // all waves done reading q_s/k_s; both become scratch (wave-private rows)

  // ones B-fragment for row-sum via MFMA, masked to key < 49 (built in registers)
  short8 on0, on1;
#pragma unroll
  for (int j = 0; j < 8; ++j) {
    on0[j] = (short)0x3F80;                                        // keys 0..31: all real
    on1[j] = (short)((32 + quad * 8 + j) < NTOK ? 0x3F80 : 0);     // keys 32..63: masked
  }

  // ---------------- Phase 2b: per head: P -> k_s (own rows), O = P v, normalize ----
#pragma unroll
  for (int h = 0; h < 3; ++h) {
#pragma unroll
    for (int nt = 0; nt < 4; ++nt) {
      unsigned short* p = &k_s[trow * STQ + 16 * nt + l15];
      unsigned d0 = pp[h][nt][0], d1 = pp[h][nt][1];
      p[0]       = (unsigned short)d0;
      p[STQ]     = (unsigned short)(d0 >> 16);
      p[2 * STQ] = (unsigned short)d1;
      p[3 * STQ] = (unsigned short)(d1 >> 16);
    }
    float4v o0 = ZERO4, o1 = ZERO4, o2 = ZERO4;
#pragma unroll
    for (int ks = 0; ks < 2; ++ks) {
      short8 pa  = *(const short8*)&k_s[(16 * wv + l15) * STQ + 32 * ks + quad * 8];
      short8 vb0 = *(const short8*)&v_sT[(32 * h + l15) * STV + 32 * ks + quad * 8];
      short8 vb1 = *(const short8*)&v_sT[(32 * h + 16 + l15) * STV + 32 * ks + quad * 8];
      o0 = __builtin_amdgcn_mfma_f32_16x16x32_bf16(pa, vb0, o0, 0, 0, 0);
      o1 = __builtin_amdgcn_mfma_f32_16x16x32_bf16(pa, vb1, o1, 0, 0, 0);
      o2 = __builtin_amdgcn_mfma_f32_16x16x32_bf16(pa, ks ? on1 : on0, o2, 0, 0, 0);
    }
    float r0 = __builtin_amdgcn_rcpf(o2[0]);
    float r1 = __builtin_amdgcn_rcpf(o2[1]);
    float r2 = __builtin_amdgcn_rcpf(o2[2]);
    float r3 = __builtin_amdgcn_rcpf(o2[3]);
    unsigned a01 = pk2(o0[0] * r0, o0[1] * r1);
    unsigned a23 = pk2(o0[2] * r2, o0[3] * r3);
    unsigned b01 = pk2(o1[0] * r0, o1[1] * r1);
    unsigned b23 = pk2(o1[2] * r2, o1[3] * r3);
    unsigned short* ar = &q_s[trow * STQ + 32 * h + l15];
    ar[0]            = (unsigned short)a01;
    ar[STQ]          = (unsigned short)(a01 >> 16);
    ar[2 * STQ]      = (unsigned short)a23;
    ar[3 * STQ]      = (unsigned short)(a23 >> 16);
    ar[16]           = (unsigned short)b01;
    ar[STQ + 16]     = (unsigned short)(b01 >> 16);
    ar[2 * STQ + 16] = (unsigned short)b23;
    ar[3 * STQ + 16] = (unsigned short)(b23 >> 16);
  }

  // ---------------- Phase 3: proj = att @ w_proj + b ----------------
  // (att in q_s own rows; no barrier needed — same-wave in-order LDS)
  const short8* bp = (const short8*)(blob + 3456 * 8);
  float4v pacc[6];
#pragma unroll
  for (int i = 0; i < 6; ++i) pacc[i] = ZERO4;
#pragma unroll
  for (int ks = 0; ks < 3; ++ks) {
    short8 aa = *(const short8*)&q_s[(16 * wv + l15) * STQ + 32 * ks + quad * 8];
#pragma unroll
    for (int nt = 0; nt < 6; ++nt) {
      short8 bf = bp[(ks * 6 + nt) * 64 + lane];
      pacc[nt] = __builtin_amdgcn_mfma_f32_16x16x32_bf16(aa, bf, pacc[nt], 0, 0, 0);
    }
  }
  float pb[6];
#pragma unroll
  for (int nt = 0; nt < 6; ++nt) pb[nt] = bproj[16 * nt + l15];
#pragma unroll
  for (int r = 0; r < 4; ++r) {
    int t = trow + r;
    if (t < NTOK) {
      int rr = t / 7, cc = t - 7 * rr;
      int gh = wr * 7 + rr + 3; if (gh >= IMG) gh -= IMG;
      int gw = wc * 7 + cc + 3; if (gw >= IMG) gw -= IMG;
      float* op = out + ((b * IMG + gh) * IMG + gw) * CDIM;
#pragma unroll
      for (int nt = 0; nt < 6; ++nt)
        op[16 * nt + l15] = pacc[nt][r] + pb[nt];
    }
  }
}

extern "C" void kernel_launch(void* const* d_in, const int* in_sizes, int n_in,
                              void* d_out, int out_size, void* d_ws, size_t ws_size,
                              hipStream_t stream) {
  const float* x      = (const float*)d_in[0];
  const float* w_qkv  = (const float*)d_in[1];
  const float* b_qkv  = (const float*)d_in[2];
  const float* w_proj = (const float*)d_in[3];
  const float* b_proj = (const float*)d_in[4];
  float* out = (float*)d_out;
  unsigned short* blob = (unsigned short*)d_ws;  // 73728 B used

  hipLaunchKernelGGL(prep_weights, dim3(18), dim3(256), 0, stream, w_qkv, w_proj, blob);
  hipLaunchKernelGGL(swin_kernel, dim3(16384), dim3(256), 0, stream,
                     x, b_qkv, b_proj, blob, out);
}